// Round 10
// baseline (9233.159 us; speedup 1.0000x reference)
//
#include <hip/hip_runtime.h>
#include <math.h>

constexpr int NT = 100000;
constexpr int NJ = 300000;
constexpr int E_TJ = 1000000, E_JT = 1000000, E_JJ = 2000000;
constexpr float SP_BIAS = 0.5413248546129181f;  // log(expm1(1.0))

// ---------------- utility ----------------
__global__ void k_zero(int* __restrict__ p, int n) {
    int i = blockIdx.x * 256 + threadIdx.x;
    if (i < n) p[i] = 0;
}

// wcomb = wa + wb (4096), bcomb = ba + bb (64)
__global__ void k_prep(const float* __restrict__ wa, const float* __restrict__ wb,
                       const float* __restrict__ ba, const float* __restrict__ bb,
                       float* __restrict__ wcomb, float* __restrict__ bcomb) {
    int i = blockIdx.x * 256 + threadIdx.x;
    if (i < 4096) wcomb[i] = wa[i] + wb[i];
    else if (i < 4160) bcomb[i - 4096] = ba[i - 4096] + bb[i - 4096];
}

// ---------------- CSR build (round-8 proven: separate kernels, 4 edges/thread) ----------------
__global__ void k_count(const int* __restrict__ dst, int E, int* __restrict__ deg) {
    int t = blockIdx.x * blockDim.x + threadIdx.x;
    int S = gridDim.x * blockDim.x;
    int e0 = t, e1 = t + S, e2 = t + 2 * S, e3 = t + 3 * S;
    int d0 = (e0 < E) ? dst[e0] : 0;
    int d1 = (e1 < E) ? dst[e1] : 0;
    int d2 = (e2 < E) ? dst[e2] : 0;
    int d3 = (e3 < E) ? dst[e3] : 0;
    if (e0 < E) atomicAdd(&deg[d0], 1);
    if (e1 < E) atomicAdd(&deg[d1], 1);
    if (e2 < E) atomicAdd(&deg[d2], 1);
    if (e3 < E) atomicAdd(&deg[d3], 1);
}

__global__ __launch_bounds__(1024) void k_bsum(const int* __restrict__ deg, int n,
                                               int* __restrict__ bsum) {
    __shared__ int s[1024];
    int i = blockIdx.x * 1024 + threadIdx.x;
    s[threadIdx.x] = (i < n) ? deg[i] : 0;
    __syncthreads();
    for (int d = 512; d > 0; d >>= 1) {
        if (threadIdx.x < d) s[threadIdx.x] += s[threadIdx.x + d];
        __syncthreads();
    }
    if (threadIdx.x == 0) bsum[blockIdx.x] = s[0];
}

__global__ __launch_bounds__(1024) void k_scan_bsum(int* bsum, int nb) {
    __shared__ int s[1024];
    int t = threadIdx.x;
    int v = (t < nb) ? bsum[t] : 0;
    s[t] = v;
    __syncthreads();
    for (int d = 1; d < 1024; d <<= 1) {
        int x = (t >= d) ? s[t - d] : 0;
        __syncthreads();
        s[t] += x;
        __syncthreads();
    }
    if (t < nb) bsum[t] = s[t] - v;  // exclusive prefix
}

__global__ __launch_bounds__(1024) void k_scan_final(const int* __restrict__ deg, int n,
                                                     const int* __restrict__ bsum,
                                                     int* __restrict__ off,
                                                     int* __restrict__ cur) {
    __shared__ int s[1024];
    int t = threadIdx.x;
    int i = blockIdx.x * 1024 + t;
    int v = (i < n) ? deg[i] : 0;
    s[t] = v;
    __syncthreads();
    for (int d = 1; d < 1024; d <<= 1) {
        int x = (t >= d) ? s[t - d] : 0;
        __syncthreads();
        s[t] += x;
        __syncthreads();
    }
    int incl = s[t];
    int base = bsum[blockIdx.x];
    if (i < n) {
        int excl = base + incl - v;
        off[i] = excl;
        cur[i] = excl;
        if (i == n - 1) off[n] = base + incl;
    }
}

// stores src index PRE-SCALED by 64; 4 edges/thread for atomic+store MLP
__global__ void k_fill(const int* __restrict__ src, const int* __restrict__ dst, int E,
                       int* __restrict__ cur, int* __restrict__ out_src, int src_ofs) {
    int t = blockIdx.x * blockDim.x + threadIdx.x;
    int S = gridDim.x * blockDim.x;
    int e0 = t, e1 = t + S, e2 = t + 2 * S, e3 = t + 3 * S;
    int d0 = (e0 < E) ? dst[e0] : 0;
    int d1 = (e1 < E) ? dst[e1] : 0;
    int d2 = (e2 < E) ? dst[e2] : 0;
    int d3 = (e3 < E) ? dst[e3] : 0;
    int s0 = (e0 < E) ? src[e0] : 0;
    int s1 = (e1 < E) ? src[e1] : 0;
    int s2 = (e2 < E) ? src[e2] : 0;
    int s3 = (e3 < E) ? src[e3] : 0;
    int p0 = 0, p1 = 0, p2 = 0, p3 = 0;
    if (e0 < E) p0 = atomicAdd(&cur[d0], 1);
    if (e1 < E) p1 = atomicAdd(&cur[d1], 1);
    if (e2 < E) p2 = atomicAdd(&cur[d2], 1);
    if (e3 < E) p3 = atomicAdd(&cur[d3], 1);
    if (e0 < E) out_src[p0] = (s0 + src_ofs) * 64;
    if (e1 < E) out_src[p1] = (s1 + src_ofs) * 64;
    if (e2 < E) out_src[p2] = (s2 + src_ofs) * 64;
    if (e3 < E) out_src[p3] = (s3 + src_ofs) * 64;
}

// ---------------- dense ops ----------------
// h = x @ w + b  (x: n x 32) — quad-node waves, LDS-broadcast matvec
__global__ __launch_bounds__(256) void k_in_linear(const float* __restrict__ x,
        const float* __restrict__ w, const float* __restrict__ b,
        float* __restrict__ h, int n) {
    __shared__ float ws_[32 * 64];
    __shared__ __align__(16) float xs_[512];
    for (int i = threadIdx.x; i < 32 * 64; i += 256) ws_[i] = w[i];
    __syncthreads();
    const int wslot = (threadIdx.x >> 6) & 3;
    const int lane = threadIdx.x & 63;
    const int lo = lane & 31;
    float* xsw = &xs_[wslot * 128];
    int wave = (blockIdx.x * 256 + threadIdx.x) >> 6;
    int nq = (n + 3) >> 2;
    int nwaves = gridDim.x * 4;
    float bv = b[lane];
    for (int q = wave; q < nq; q += nwaves) {
        int i0 = q * 4;
        int i1 = i0 + 1 < n ? i0 + 1 : n - 1;
        int i2 = i0 + 2 < n ? i0 + 2 : n - 1;
        int i3 = i0 + 3 < n ? i0 + 3 : n - 1;
        xsw[lane]      = (lane < 32) ? x[(size_t)i0 * 32 + lo] : x[(size_t)i1 * 32 + lo];
        xsw[64 + lane] = (lane < 32) ? x[(size_t)i2 * 32 + lo] : x[(size_t)i3 * 32 + lo];
        float r0 = bv, r1 = bv, r2 = bv, r3 = bv;
        const float4* xq = (const float4*)xsw;
        #pragma unroll
        for (int c = 0; c < 8; ++c) {
            float4 x0 = xq[c], x1 = xq[8 + c], x2 = xq[16 + c], x3 = xq[24 + c];
            float wA = ws_[(4 * c + 0) * 64 + lane];
            float wB = ws_[(4 * c + 1) * 64 + lane];
            float wC = ws_[(4 * c + 2) * 64 + lane];
            float wD = ws_[(4 * c + 3) * 64 + lane];
            r0 += x0.x * wA + x0.y * wB + x0.z * wC + x0.w * wD;
            r1 += x1.x * wA + x1.y * wB + x1.z * wC + x1.w * wD;
            r2 += x2.x * wA + x2.y * wB + x2.z * wC + x2.w * wD;
            r3 += x3.x * wA + x3.y * wB + x3.z * wC + x3.w * wD;
        }
        h[(size_t)i0 * 64 + lane] = r0;
        if (i0 + 1 < n) h[(size_t)i1 * 64 + lane] = r1;
        if (i0 + 2 < n) h[(size_t)i2 * 64 + lane] = r2;
        if (i0 + 3 < n) h[(size_t)i3 * 64 + lane] = r3;
    }
}

// aout = hin @ w (+bias)  — weights in REGISTERS (lane = output column, 64 VGPRs),
// quad-node waves, h broadcast via uniform (conflict-free) LDS b128 reads.
// In-place safe when aout==hin (wave reads its rows before writing them).
__global__ __launch_bounds__(256, 4) void k_mm(const float* __restrict__ hin,
        const float* __restrict__ w, const float* __restrict__ bias,
        float* __restrict__ aout, int n) {
    const int lane = threadIdx.x & 63;
    float wr[64];
    #pragma unroll
    for (int k = 0; k < 64; ++k) wr[k] = w[k * 64 + lane];  // coalesced; L2-resident
    float bv = bias ? bias[lane] : 0.f;
    __shared__ __align__(16) float hs_[1024];
    const int wslot = (threadIdx.x >> 6) & 3;
    float* hsw = &hs_[wslot * 256];
    int wave = (blockIdx.x * 256 + threadIdx.x) >> 6;
    int nq = (n + 3) >> 2;
    int nwaves = gridDim.x * 4;
    for (int q = wave; q < nq; q += nwaves) {
        int i0 = q * 4;
        int i1 = i0 + 1 < n ? i0 + 1 : n - 1;
        int i2 = i0 + 2 < n ? i0 + 2 : n - 1;
        int i3 = i0 + 3 < n ? i0 + 3 : n - 1;
        hsw[lane]       = hin[(size_t)i0 * 64 + lane];
        hsw[64 + lane]  = hin[(size_t)i1 * 64 + lane];
        hsw[128 + lane] = hin[(size_t)i2 * 64 + lane];
        hsw[192 + lane] = hin[(size_t)i3 * 64 + lane];
        float r0 = bv, r1 = bv, r2 = bv, r3 = bv;
        const float4* hq = (const float4*)hsw;
        #pragma unroll
        for (int c = 0; c < 16; ++c) {
            float4 h0 = hq[c], h1 = hq[16 + c], h2 = hq[32 + c], h3 = hq[48 + c];
            float wA = wr[4 * c + 0], wB = wr[4 * c + 1];
            float wC = wr[4 * c + 2], wD = wr[4 * c + 3];
            r0 += h0.x * wA + h0.y * wB + h0.z * wC + h0.w * wD;
            r1 += h1.x * wA + h1.y * wB + h1.z * wC + h1.w * wD;
            r2 += h2.x * wA + h2.y * wB + h2.z * wC + h2.w * wD;
            r3 += h3.x * wA + h3.y * wB + h3.z * wC + h3.w * wD;
        }
        aout[(size_t)i0 * 64 + lane] = r0;
        if (i0 + 1 < n) aout[(size_t)i1 * 64 + lane] = r1;
        if (i0 + 2 < n) aout[(size_t)i2 * 64 + lane] = r2;
        if (i0 + 3 < n) aout[(size_t)i3 * 64 + lane] = r3;
    }
}

// h[i] = tanh( sum_e a[src_e] + h[i] )  — h holds root term; srcs pre-scaled by 64.
// Register-lean single-node waves (round-7 proven form).
__global__ __launch_bounds__(256) void k_aggadd(const float* __restrict__ a,
        float* __restrict__ h,
        const int* __restrict__ off, const int* __restrict__ srcs, int n) {
    int wave = (blockIdx.x * 256 + threadIdx.x) >> 6;
    int lane = threadIdx.x & 63;
    int nwaves = gridDim.x * 4;
    for (int i = wave; i < n; i += nwaves) {
        int e0 = off[i], e1 = off[i + 1];
        float acc = h[(size_t)i * 64 + lane];
        for (int base = e0; base < e1; base += 64) {
            int rem = e1 - base;
            int cnt = rem < 64 ? rem : 64;
            int idx = (lane < cnt) ? srcs[base + lane] : 0;
            int k = 0;
            for (; k + 8 <= cnt; k += 8) {
                int s0 = __shfl(idx, k),     s1 = __shfl(idx, k + 1);
                int s2 = __shfl(idx, k + 2), s3 = __shfl(idx, k + 3);
                int s4 = __shfl(idx, k + 4), s5 = __shfl(idx, k + 5);
                int s6 = __shfl(idx, k + 6), s7 = __shfl(idx, k + 7);
                float v0 = a[(size_t)s0 + lane], v1 = a[(size_t)s1 + lane];
                float v2 = a[(size_t)s2 + lane], v3 = a[(size_t)s3 + lane];
                float v4 = a[(size_t)s4 + lane], v5 = a[(size_t)s5 + lane];
                float v6 = a[(size_t)s6 + lane], v7 = a[(size_t)s7 + lane];
                acc += ((v0 + v1) + (v2 + v3)) + ((v4 + v5) + (v6 + v7));
            }
            for (; k < cnt; ++k)
                acc += a[(size_t)__shfl(idx, k) + lane];
        }
        h[(size_t)i * 64 + lane] = tanhf(acc);
    }
}

// o = tanh(h @ w3 + b3); loc = o[:8], scale = softplus(o[8:] + SP_BIAS)
__global__ __launch_bounds__(256) void k_out(const float* __restrict__ h,
        const float* __restrict__ w3, const float* __restrict__ b3,
        float* __restrict__ loc, float* __restrict__ scale, int n) {
    __shared__ float ws_[64 * 16];
    __shared__ __align__(16) float hs_[1024];
    for (int i = threadIdx.x; i < 64 * 16; i += 256) ws_[i] = w3[i];
    __syncthreads();
    const int wslot = (threadIdx.x >> 6) & 3;
    const int lane = threadIdx.x & 63;
    const int m = lane >> 4;
    const int o = lane & 15;
    float* hsw = &hs_[wslot * 256];
    int wave = (blockIdx.x * 256 + threadIdx.x) >> 6;
    int nq = (n + 3) >> 2;
    int nwaves = gridDim.x * 4;
    float bv = b3[o];
    for (int q = wave; q < nq; q += nwaves) {
        int i0 = q * 4;
        int i1 = i0 + 1 < n ? i0 + 1 : n - 1;
        int i2 = i0 + 2 < n ? i0 + 2 : n - 1;
        int i3 = i0 + 3 < n ? i0 + 3 : n - 1;
        hsw[lane]       = h[(size_t)i0 * 64 + lane];
        hsw[64 + lane]  = h[(size_t)i1 * 64 + lane];
        hsw[128 + lane] = h[(size_t)i2 * 64 + lane];
        hsw[192 + lane] = h[(size_t)i3 * 64 + lane];
        float acc = bv;
        const float4* hq = (const float4*)&hsw[m * 64];
        #pragma unroll
        for (int c = 0; c < 16; ++c) {
            float4 hv = hq[c];
            acc += hv.x * ws_[(4 * c + 0) * 16 + o];
            acc += hv.y * ws_[(4 * c + 1) * 16 + o];
            acc += hv.z * ws_[(4 * c + 2) * 16 + o];
            acc += hv.w * ws_[(4 * c + 3) * 16 + o];
        }
        int im = (m == 0) ? i0 : (m == 1) ? i1 : (m == 2) ? i2 : i3;
        bool valid = (i0 + m < n) || (m == 0);
        float v = tanhf(acc);
        if (valid) {
            if (o < 8) {
                loc[(size_t)im * 8 + o] = v;
            } else {
                float xx = v + SP_BIAS;
                float sp = (xx > 20.f) ? xx : log1pf(expf(xx));
                scale[(size_t)im * 8 + (o - 8)] = sp;
            }
        }
    }
}

// ---------------- launch ----------------
extern "C" void kernel_launch(void* const* d_in, const int* in_sizes, int n_in,
                              void* d_out, int out_size, void* d_ws, size_t ws_size,
                              hipStream_t stream) {
    const float* x_t  = (const float*)d_in[0];
    const float* x_j  = (const float*)d_in[1];
    const int*   ei_tj = (const int*)d_in[2];
    const int*   ei_jt = (const int*)d_in[3];
    const int*   ei_jj = (const int*)d_in[4];
    const float* w0_t = (const float*)d_in[5];
    const float* b0_t = (const float*)d_in[6];
    const float* w0_j = (const float*)d_in[7];
    const float* b0_j = (const float*)d_in[8];
    const float* w3_t = (const float*)d_in[27];
    const float* b3_t = (const float*)d_in[28];
    const float* w3_j = (const float*)d_in[29];
    const float* b3_j = (const float*)d_in[30];

    // workspace layout: Q and P MUST be contiguous ([Q;P] combined index space)
    float* fws   = (float*)d_ws;
    float* Q     = fws;                              // NT*64 (transformed torso)
    float* P     = Q + (size_t)NT * 64;              // NJ*64 (transformed joint, reused twice)
    float* h_t   = P + (size_t)NJ * 64;              // NT*64
    float* h_j   = h_t + (size_t)NT * 64;            // NJ*64
    float* wcomb = h_j + (size_t)NJ * 64;            // 64*64
    float* bcomb = wcomb + 64 * 64;                  // 64
    int* iws    = (int*)(bcomb + 64);
    int* off_jt = iws;                               // NT+1
    int* cur_jt = off_jt + NT + 1;                   // NT
    int* off_cj = cur_jt + NT;                       // NJ+1  (combined tj+jj -> joint)
    int* cur_cj = off_cj + NJ + 1;                   // NJ
    int* src_jt = cur_cj + NJ;                       // E_JT
    int* src_cj = src_jt + E_JT;                     // E_TJ + E_JJ
    int* bsum   = src_cj + E_TJ + E_JJ;              // 1024

    size_t required = ((char*)(bsum + 1024)) - ((char*)d_ws);
    if (ws_size < required) return;  // distinguishable failure (output stays poisoned)

    // ---- CSR build (edges identical both layers) ----
    int zcount = 2 * NT + 2 * NJ + 2;
    k_zero<<<(zcount + 255) / 256, 256, 0, stream>>>(iws, zcount);
    k_count<<<(E_JT / 4 + 255) / 256, 256, 0, stream>>>(ei_jt + E_JT, E_JT, cur_jt);
    k_count<<<(E_TJ / 4 + 255) / 256, 256, 0, stream>>>(ei_tj + E_TJ, E_TJ, cur_cj);
    k_count<<<(E_JJ / 4 + 255) / 256, 256, 0, stream>>>(ei_jj + E_JJ, E_JJ, cur_cj);

    auto scan = [&](int* cur, int* off, int n) {
        int nb = (n + 1023) / 1024;
        k_bsum<<<nb, 1024, 0, stream>>>(cur, n, bsum);
        k_scan_bsum<<<1, 1024, 0, stream>>>(bsum, nb);
        k_scan_final<<<nb, 1024, 0, stream>>>(cur, n, bsum, off, cur);
    };
    scan(cur_jt, off_jt, NT);
    scan(cur_cj, off_cj, NJ);

    k_fill<<<(E_JT / 4 + 255) / 256, 256, 0, stream>>>(ei_jt, ei_jt + E_JT, E_JT, cur_jt, src_jt, 0);
    // combined joint CSR: tj sources -> Q rows [0,NT); jj sources -> P rows via +NT
    k_fill<<<(E_TJ / 4 + 255) / 256, 256, 0, stream>>>(ei_tj, ei_tj + E_TJ, E_TJ, cur_cj, src_cj, 0);
    k_fill<<<(E_JJ / 4 + 255) / 256, 256, 0, stream>>>(ei_jj, ei_jj + E_JJ, E_JJ, cur_cj, src_cj, NT);

    // ---- input linears ----
    k_in_linear<<<2048, 256, 0, stream>>>(x_t, w0_t, b0_t, h_t, NT);
    k_in_linear<<<2048, 256, 0, stream>>>(x_j, w0_j, b0_j, h_j, NJ);

    // ---- 2 hetero GraphConv layers ----
    for (int l = 0; l < 2; ++l) {
        const float* tj_rel_w  = (const float*)d_in[9 + l * 9 + 0];
        const float* tj_rel_b  = (const float*)d_in[9 + l * 9 + 1];
        const float* tj_root_w = (const float*)d_in[9 + l * 9 + 2];
        const float* jt_rel_w  = (const float*)d_in[9 + l * 9 + 3];
        const float* jt_rel_b  = (const float*)d_in[9 + l * 9 + 4];
        const float* jt_root_w = (const float*)d_in[9 + l * 9 + 5];
        const float* jj_rel_w  = (const float*)d_in[9 + l * 9 + 6];
        const float* jj_rel_b  = (const float*)d_in[9 + l * 9 + 7];
        const float* jj_root_w = (const float*)d_in[9 + l * 9 + 8];

        k_prep<<<17, 256, 0, stream>>>(tj_root_w, jj_root_w, tj_rel_b, jj_rel_b, wcomb, bcomb);

        // Q = old h_t @ W_tj  (must precede in-place h_t update)
        k_mm<<<2048, 256, 0, stream>>>(h_t, tj_rel_w, nullptr, Q, NT);
        // h_t <- old h_t @ root_jt + b_jt   (in place)
        k_mm<<<2048, 256, 0, stream>>>(h_t, jt_root_w, jt_rel_b, h_t, NT);
        // P = h_j @ W_jt
        k_mm<<<2048, 256, 0, stream>>>(h_j, jt_rel_w, nullptr, P, NJ);
        // h_t = tanh( gather_jt(P) + h_t )
        k_aggadd<<<2048, 256, 0, stream>>>(P, h_t, off_jt, src_jt, NT);
        // P = h_j @ W_jj  (old P consumed above; h_j still old)
        k_mm<<<2048, 256, 0, stream>>>(h_j, jj_rel_w, nullptr, P, NJ);
        // h_j <- h_j @ wcomb + bcomb   (in place, after both h_j reads)
        k_mm<<<2048, 256, 0, stream>>>(h_j, wcomb, bcomb, h_j, NJ);
        // h_j = tanh( gather_cj([Q;P]) + h_j )
        k_aggadd<<<2048, 256, 0, stream>>>(Q, h_j, off_cj, src_cj, NJ);
    }

    // ---- output heads ----
    float* out = (float*)d_out;
    k_out<<<2048, 256, 0, stream>>>(h_t, w3_t, b3_t,
                                    out, out + (size_t)NT * 8, NT);
    k_out<<<2048, 256, 0, stream>>>(h_j, w3_j, b3_j,
                                    out + (size_t)2 * NT * 8,
                                    out + (size_t)2 * NT * 8 + (size_t)NJ * 8, NJ);
}

// Round 11
// 1336.981 us; speedup vs baseline: 6.9060x; 6.9060x over previous
//
#include <hip/hip_runtime.h>
#include <math.h>

constexpr int NT = 100000;
constexpr int NJ = 300000;
constexpr int E_TJ = 1000000, E_JT = 1000000, E_JJ = 2000000;
constexpr float SP_BIAS = 0.5413248546129181f;  // log(expm1(1.0))

// ---------------- utility ----------------
__global__ void k_zero(int* __restrict__ p, int n) {
    int i = blockIdx.x * 256 + threadIdx.x;
    if (i < n) p[i] = 0;
}

// wcomb = wa + wb (4096), bcomb = ba + bb (64)
__global__ void k_prep(const float* __restrict__ wa, const float* __restrict__ wb,
                       const float* __restrict__ ba, const float* __restrict__ bb,
                       float* __restrict__ wcomb, float* __restrict__ bcomb) {
    int i = blockIdx.x * 256 + threadIdx.x;
    if (i < 4096) wcomb[i] = wa[i] + wb[i];
    else if (i < 4160) bcomb[i - 4096] = ba[i - 4096] + bb[i - 4096];
}

// ---------------- CSR build (separate kernels, 4 edges/thread — round-8 proven) ----------------
__global__ void k_count(const int* __restrict__ dst, int E, int* __restrict__ deg) {
    int t = blockIdx.x * blockDim.x + threadIdx.x;
    int S = gridDim.x * blockDim.x;
    int e0 = t, e1 = t + S, e2 = t + 2 * S, e3 = t + 3 * S;
    int d0 = (e0 < E) ? dst[e0] : 0;
    int d1 = (e1 < E) ? dst[e1] : 0;
    int d2 = (e2 < E) ? dst[e2] : 0;
    int d3 = (e3 < E) ? dst[e3] : 0;
    if (e0 < E) atomicAdd(&deg[d0], 1);
    if (e1 < E) atomicAdd(&deg[d1], 1);
    if (e2 < E) atomicAdd(&deg[d2], 1);
    if (e3 < E) atomicAdd(&deg[d3], 1);
}

__global__ __launch_bounds__(1024) void k_bsum(const int* __restrict__ deg, int n,
                                               int* __restrict__ bsum) {
    __shared__ int s[1024];
    int i = blockIdx.x * 1024 + threadIdx.x;
    s[threadIdx.x] = (i < n) ? deg[i] : 0;
    __syncthreads();
    for (int d = 512; d > 0; d >>= 1) {
        if (threadIdx.x < d) s[threadIdx.x] += s[threadIdx.x + d];
        __syncthreads();
    }
    if (threadIdx.x == 0) bsum[blockIdx.x] = s[0];
}

__global__ __launch_bounds__(1024) void k_scan_bsum(int* bsum, int nb) {
    __shared__ int s[1024];
    int t = threadIdx.x;
    int v = (t < nb) ? bsum[t] : 0;
    s[t] = v;
    __syncthreads();
    for (int d = 1; d < 1024; d <<= 1) {
        int x = (t >= d) ? s[t - d] : 0;
        __syncthreads();
        s[t] += x;
        __syncthreads();
    }
    if (t < nb) bsum[t] = s[t] - v;  // exclusive prefix
}

__global__ __launch_bounds__(1024) void k_scan_final(const int* __restrict__ deg, int n,
                                                     const int* __restrict__ bsum,
                                                     int* __restrict__ off,
                                                     int* __restrict__ cur) {
    __shared__ int s[1024];
    int t = threadIdx.x;
    int i = blockIdx.x * 1024 + t;
    int v = (i < n) ? deg[i] : 0;
    s[t] = v;
    __syncthreads();
    for (int d = 1; d < 1024; d <<= 1) {
        int x = (t >= d) ? s[t - d] : 0;
        __syncthreads();
        s[t] += x;
        __syncthreads();
    }
    int incl = s[t];
    int base = bsum[blockIdx.x];
    if (i < n) {
        int excl = base + incl - v;
        off[i] = excl;
        cur[i] = excl;
        if (i == n - 1) off[n] = base + incl;
    }
}

// stores src index PRE-SCALED by 64; 4 edges/thread for atomic+store MLP
__global__ void k_fill(const int* __restrict__ src, const int* __restrict__ dst, int E,
                       int* __restrict__ cur, int* __restrict__ out_src, int src_ofs) {
    int t = blockIdx.x * blockDim.x + threadIdx.x;
    int S = gridDim.x * blockDim.x;
    int e0 = t, e1 = t + S, e2 = t + 2 * S, e3 = t + 3 * S;
    int d0 = (e0 < E) ? dst[e0] : 0;
    int d1 = (e1 < E) ? dst[e1] : 0;
    int d2 = (e2 < E) ? dst[e2] : 0;
    int d3 = (e3 < E) ? dst[e3] : 0;
    int s0 = (e0 < E) ? src[e0] : 0;
    int s1 = (e1 < E) ? src[e1] : 0;
    int s2 = (e2 < E) ? src[e2] : 0;
    int s3 = (e3 < E) ? src[e3] : 0;
    int p0 = 0, p1 = 0, p2 = 0, p3 = 0;
    if (e0 < E) p0 = atomicAdd(&cur[d0], 1);
    if (e1 < E) p1 = atomicAdd(&cur[d1], 1);
    if (e2 < E) p2 = atomicAdd(&cur[d2], 1);
    if (e3 < E) p3 = atomicAdd(&cur[d3], 1);
    if (e0 < E) out_src[p0] = (s0 + src_ofs) * 64;
    if (e1 < E) out_src[p1] = (s1 + src_ofs) * 64;
    if (e2 < E) out_src[p2] = (s2 + src_ofs) * 64;
    if (e3 < E) out_src[p3] = (s3 + src_ofs) * 64;
}

// ---------------- dense ops ----------------
// h = x @ w + b  (x: n x 32) — quad-node waves, LDS-broadcast matvec
__global__ __launch_bounds__(256) void k_in_linear(const float* __restrict__ x,
        const float* __restrict__ w, const float* __restrict__ b,
        float* __restrict__ h, int n) {
    __shared__ float ws_[32 * 64];
    __shared__ __align__(16) float xs_[512];
    for (int i = threadIdx.x; i < 32 * 64; i += 256) ws_[i] = w[i];
    __syncthreads();
    const int wslot = (threadIdx.x >> 6) & 3;
    const int lane = threadIdx.x & 63;
    const int lo = lane & 31;
    float* xsw = &xs_[wslot * 128];
    int wave = (blockIdx.x * 256 + threadIdx.x) >> 6;
    int nq = (n + 3) >> 2;
    int nwaves = gridDim.x * 4;
    float bv = b[lane];
    for (int q = wave; q < nq; q += nwaves) {
        int i0 = q * 4;
        int i1 = i0 + 1 < n ? i0 + 1 : n - 1;
        int i2 = i0 + 2 < n ? i0 + 2 : n - 1;
        int i3 = i0 + 3 < n ? i0 + 3 : n - 1;
        xsw[lane]      = (lane < 32) ? x[(size_t)i0 * 32 + lo] : x[(size_t)i1 * 32 + lo];
        xsw[64 + lane] = (lane < 32) ? x[(size_t)i2 * 32 + lo] : x[(size_t)i3 * 32 + lo];
        float r0 = bv, r1 = bv, r2 = bv, r3 = bv;
        const float4* xq = (const float4*)xsw;
        #pragma unroll
        for (int c = 0; c < 8; ++c) {
            float4 x0 = xq[c], x1 = xq[8 + c], x2 = xq[16 + c], x3 = xq[24 + c];
            float wA = ws_[(4 * c + 0) * 64 + lane];
            float wB = ws_[(4 * c + 1) * 64 + lane];
            float wC = ws_[(4 * c + 2) * 64 + lane];
            float wD = ws_[(4 * c + 3) * 64 + lane];
            r0 += x0.x * wA + x0.y * wB + x0.z * wC + x0.w * wD;
            r1 += x1.x * wA + x1.y * wB + x1.z * wC + x1.w * wD;
            r2 += x2.x * wA + x2.y * wB + x2.z * wC + x2.w * wD;
            r3 += x3.x * wA + x3.y * wB + x3.z * wC + x3.w * wD;
        }
        h[(size_t)i0 * 64 + lane] = r0;
        if (i0 + 1 < n) h[(size_t)i1 * 64 + lane] = r1;
        if (i0 + 2 < n) h[(size_t)i2 * 64 + lane] = r2;
        if (i0 + 3 < n) h[(size_t)i3 * 64 + lane] = r3;
    }
}

// a = h @ w  (64x64) — quad-node waves, LDS weights, (256,4) + unroll 4 (round-7 proven)
__global__ __launch_bounds__(256, 4) void k_transform(const float* __restrict__ h,
        const float* __restrict__ w, float* __restrict__ a, int n) {
    __shared__ float ws_[64 * 64];
    __shared__ __align__(16) float hs_[1024];
    for (int i = threadIdx.x; i < 64 * 64; i += 256) ws_[i] = w[i];
    __syncthreads();
    const int wslot = (threadIdx.x >> 6) & 3;
    const int lane = threadIdx.x & 63;
    float* hsw = &hs_[wslot * 256];
    int wave = (blockIdx.x * 256 + threadIdx.x) >> 6;
    int nq = (n + 3) >> 2;
    int nwaves = gridDim.x * 4;
    for (int q = wave; q < nq; q += nwaves) {
        int i0 = q * 4;
        int i1 = i0 + 1 < n ? i0 + 1 : n - 1;
        int i2 = i0 + 2 < n ? i0 + 2 : n - 1;
        int i3 = i0 + 3 < n ? i0 + 3 : n - 1;
        hsw[lane]       = h[(size_t)i0 * 64 + lane];
        hsw[64 + lane]  = h[(size_t)i1 * 64 + lane];
        hsw[128 + lane] = h[(size_t)i2 * 64 + lane];
        hsw[192 + lane] = h[(size_t)i3 * 64 + lane];
        float r0 = 0.f, r1 = 0.f, r2 = 0.f, r3 = 0.f;
        const float4* hq = (const float4*)hsw;
        #pragma unroll 4
        for (int c = 0; c < 16; ++c) {
            float4 h0 = hq[c], h1 = hq[16 + c], h2 = hq[32 + c], h3 = hq[48 + c];
            float wA = ws_[(4 * c + 0) * 64 + lane];
            float wB = ws_[(4 * c + 1) * 64 + lane];
            float wC = ws_[(4 * c + 2) * 64 + lane];
            float wD = ws_[(4 * c + 3) * 64 + lane];
            r0 += h0.x * wA + h0.y * wB + h0.z * wC + h0.w * wD;
            r1 += h1.x * wA + h1.y * wB + h1.z * wC + h1.w * wD;
            r2 += h2.x * wA + h2.y * wB + h2.z * wC + h2.w * wD;
            r3 += h3.x * wA + h3.y * wB + h3.z * wC + h3.w * wD;
        }
        a[(size_t)i0 * 64 + lane] = r0;
        if (i0 + 1 < n) a[(size_t)i1 * 64 + lane] = r1;
        if (i0 + 2 < n) a[(size_t)i2 * 64 + lane] = r2;
        if (i0 + 3 < n) a[(size_t)i3 * 64 + lane] = r3;
    }
}

// dual transform: outa = h @ wa ;  h = h @ wb + bias  (in place, row-local)
__global__ __launch_bounds__(256, 4) void k_transform2(float* __restrict__ h,
        const float* __restrict__ wa, const float* __restrict__ wb,
        const float* __restrict__ bias, float* __restrict__ outa, int n) {
    __shared__ float wsa_[64 * 64];
    __shared__ float wsb_[64 * 64];
    __shared__ __align__(16) float hs_[1024];
    for (int i = threadIdx.x; i < 64 * 64; i += 256) { wsa_[i] = wa[i]; wsb_[i] = wb[i]; }
    __syncthreads();
    const int wslot = (threadIdx.x >> 6) & 3;
    const int lane = threadIdx.x & 63;
    float* hsw = &hs_[wslot * 256];
    int wave = (blockIdx.x * 256 + threadIdx.x) >> 6;
    int nq = (n + 3) >> 2;
    int nwaves = gridDim.x * 4;
    float bv = bias[lane];
    for (int q = wave; q < nq; q += nwaves) {
        int i0 = q * 4;
        int i1 = i0 + 1 < n ? i0 + 1 : n - 1;
        int i2 = i0 + 2 < n ? i0 + 2 : n - 1;
        int i3 = i0 + 3 < n ? i0 + 3 : n - 1;
        hsw[lane]       = h[(size_t)i0 * 64 + lane];
        hsw[64 + lane]  = h[(size_t)i1 * 64 + lane];
        hsw[128 + lane] = h[(size_t)i2 * 64 + lane];
        hsw[192 + lane] = h[(size_t)i3 * 64 + lane];
        float ra0 = 0.f, ra1 = 0.f, ra2 = 0.f, ra3 = 0.f;
        float rb0 = bv, rb1 = bv, rb2 = bv, rb3 = bv;
        const float4* hq = (const float4*)hsw;
        #pragma unroll 4
        for (int c = 0; c < 16; ++c) {
            float4 h0 = hq[c], h1 = hq[16 + c], h2 = hq[32 + c], h3 = hq[48 + c];
            float aA = wsa_[(4 * c + 0) * 64 + lane];
            float aB = wsa_[(4 * c + 1) * 64 + lane];
            float aC = wsa_[(4 * c + 2) * 64 + lane];
            float aD = wsa_[(4 * c + 3) * 64 + lane];
            ra0 += h0.x * aA + h0.y * aB + h0.z * aC + h0.w * aD;
            ra1 += h1.x * aA + h1.y * aB + h1.z * aC + h1.w * aD;
            ra2 += h2.x * aA + h2.y * aB + h2.z * aC + h2.w * aD;
            ra3 += h3.x * aA + h3.y * aB + h3.z * aC + h3.w * aD;
            float bA = wsb_[(4 * c + 0) * 64 + lane];
            float bB = wsb_[(4 * c + 1) * 64 + lane];
            float bC = wsb_[(4 * c + 2) * 64 + lane];
            float bD = wsb_[(4 * c + 3) * 64 + lane];
            rb0 += h0.x * bA + h0.y * bB + h0.z * bC + h0.w * bD;
            rb1 += h1.x * bA + h1.y * bB + h1.z * bC + h1.w * bD;
            rb2 += h2.x * bA + h2.y * bB + h2.z * bC + h2.w * bD;
            rb3 += h3.x * bA + h3.y * bB + h3.z * bC + h3.w * bD;
        }
        outa[(size_t)i0 * 64 + lane] = ra0;
        h[(size_t)i0 * 64 + lane] = rb0;
        if (i0 + 1 < n) { outa[(size_t)i1 * 64 + lane] = ra1; h[(size_t)i1 * 64 + lane] = rb1; }
        if (i0 + 2 < n) { outa[(size_t)i2 * 64 + lane] = ra2; h[(size_t)i2 * 64 + lane] = rb2; }
        if (i0 + 3 < n) { outa[(size_t)i3 * 64 + lane] = ra3; h[(size_t)i3 * 64 + lane] = rb3; }
    }
}

// h[i] = tanh( sum_e a[src_e] + h[i] )  — h holds root term; srcs pre-scaled by 64.
// Register-lean single-node waves (round-7 proven form).
__global__ __launch_bounds__(256) void k_aggadd(const float* __restrict__ a,
        float* __restrict__ h,
        const int* __restrict__ off, const int* __restrict__ srcs, int n) {
    int wave = (blockIdx.x * 256 + threadIdx.x) >> 6;
    int lane = threadIdx.x & 63;
    int nwaves = gridDim.x * 4;
    for (int i = wave; i < n; i += nwaves) {
        int e0 = off[i], e1 = off[i + 1];
        float acc = h[(size_t)i * 64 + lane];
        for (int base = e0; base < e1; base += 64) {
            int rem = e1 - base;
            int cnt = rem < 64 ? rem : 64;
            int idx = (lane < cnt) ? srcs[base + lane] : 0;
            int k = 0;
            for (; k + 8 <= cnt; k += 8) {
                int s0 = __shfl(idx, k),     s1 = __shfl(idx, k + 1);
                int s2 = __shfl(idx, k + 2), s3 = __shfl(idx, k + 3);
                int s4 = __shfl(idx, k + 4), s5 = __shfl(idx, k + 5);
                int s6 = __shfl(idx, k + 6), s7 = __shfl(idx, k + 7);
                float v0 = a[(size_t)s0 + lane], v1 = a[(size_t)s1 + lane];
                float v2 = a[(size_t)s2 + lane], v3 = a[(size_t)s3 + lane];
                float v4 = a[(size_t)s4 + lane], v5 = a[(size_t)s5 + lane];
                float v6 = a[(size_t)s6 + lane], v7 = a[(size_t)s7 + lane];
                acc += ((v0 + v1) + (v2 + v3)) + ((v4 + v5) + (v6 + v7));
            }
            for (; k < cnt; ++k)
                acc += a[(size_t)__shfl(idx, k) + lane];
        }
        h[(size_t)i * 64 + lane] = tanhf(acc);
    }
}

// o = tanh(h @ w3 + b3); loc = o[:8], scale = softplus(o[8:] + SP_BIAS)
__global__ __launch_bounds__(256) void k_out(const float* __restrict__ h,
        const float* __restrict__ w3, const float* __restrict__ b3,
        float* __restrict__ loc, float* __restrict__ scale, int n) {
    __shared__ float ws_[64 * 16];
    __shared__ __align__(16) float hs_[1024];
    for (int i = threadIdx.x; i < 64 * 16; i += 256) ws_[i] = w3[i];
    __syncthreads();
    const int wslot = (threadIdx.x >> 6) & 3;
    const int lane = threadIdx.x & 63;
    const int m = lane >> 4;
    const int o = lane & 15;
    float* hsw = &hs_[wslot * 256];
    int wave = (blockIdx.x * 256 + threadIdx.x) >> 6;
    int nq = (n + 3) >> 2;
    int nwaves = gridDim.x * 4;
    float bv = b3[o];
    for (int q = wave; q < nq; q += nwaves) {
        int i0 = q * 4;
        int i1 = i0 + 1 < n ? i0 + 1 : n - 1;
        int i2 = i0 + 2 < n ? i0 + 2 : n - 1;
        int i3 = i0 + 3 < n ? i0 + 3 : n - 1;
        hsw[lane]       = h[(size_t)i0 * 64 + lane];
        hsw[64 + lane]  = h[(size_t)i1 * 64 + lane];
        hsw[128 + lane] = h[(size_t)i2 * 64 + lane];
        hsw[192 + lane] = h[(size_t)i3 * 64 + lane];
        float acc = bv;
        const float4* hq = (const float4*)&hsw[m * 64];
        #pragma unroll
        for (int c = 0; c < 16; ++c) {
            float4 hv = hq[c];
            acc += hv.x * ws_[(4 * c + 0) * 16 + o];
            acc += hv.y * ws_[(4 * c + 1) * 16 + o];
            acc += hv.z * ws_[(4 * c + 2) * 16 + o];
            acc += hv.w * ws_[(4 * c + 3) * 16 + o];
        }
        int im = (m == 0) ? i0 : (m == 1) ? i1 : (m == 2) ? i2 : i3;
        bool valid = (i0 + m < n) || (m == 0);
        float v = tanhf(acc);
        if (valid) {
            if (o < 8) {
                loc[(size_t)im * 8 + o] = v;
            } else {
                float xx = v + SP_BIAS;
                float sp = (xx > 20.f) ? xx : log1pf(expf(xx));
                scale[(size_t)im * 8 + (o - 8)] = sp;
            }
        }
    }
}

// ---------------- launch ----------------
extern "C" void kernel_launch(void* const* d_in, const int* in_sizes, int n_in,
                              void* d_out, int out_size, void* d_ws, size_t ws_size,
                              hipStream_t stream) {
    const float* x_t  = (const float*)d_in[0];
    const float* x_j  = (const float*)d_in[1];
    const int*   ei_tj = (const int*)d_in[2];
    const int*   ei_jt = (const int*)d_in[3];
    const int*   ei_jj = (const int*)d_in[4];
    const float* w0_t = (const float*)d_in[5];
    const float* b0_t = (const float*)d_in[6];
    const float* w0_j = (const float*)d_in[7];
    const float* b0_j = (const float*)d_in[8];
    const float* w3_t = (const float*)d_in[27];
    const float* b3_t = (const float*)d_in[28];
    const float* w3_j = (const float*)d_in[29];
    const float* b3_j = (const float*)d_in[30];

    // workspace layout: Q and P MUST be contiguous ([Q;P] combined index space)
    float* fws   = (float*)d_ws;
    float* Q     = fws;                              // NT*64 (transformed torso)
    float* P     = Q + (size_t)NT * 64;              // NJ*64 (transformed joint, reused twice)
    float* h_t   = P + (size_t)NJ * 64;              // NT*64
    float* h_j   = h_t + (size_t)NT * 64;            // NJ*64
    float* wcomb = h_j + (size_t)NJ * 64;            // 64*64
    float* bcomb = wcomb + 64 * 64;                  // 64
    int* iws    = (int*)(bcomb + 64);
    int* off_jt = iws;                               // NT+1
    int* cur_jt = off_jt + NT + 1;                   // NT
    int* off_cj = cur_jt + NT;                       // NJ+1  (combined tj+jj -> joint)
    int* cur_cj = off_cj + NJ + 1;                   // NJ
    int* src_jt = cur_cj + NJ;                       // E_JT
    int* src_cj = src_jt + E_JT;                     // E_TJ + E_JJ
    int* bsum   = src_cj + E_TJ + E_JJ;              // 1024

    size_t required = ((char*)(bsum + 1024)) - ((char*)d_ws);
    if (ws_size < required) return;  // distinguishable failure (output stays poisoned)

    // ---- CSR build (edges identical both layers) ----
    int zcount = 2 * NT + 2 * NJ + 2;
    k_zero<<<(zcount + 255) / 256, 256, 0, stream>>>(iws, zcount);
    k_count<<<(E_JT / 4 + 255) / 256, 256, 0, stream>>>(ei_jt + E_JT, E_JT, cur_jt);
    k_count<<<(E_TJ / 4 + 255) / 256, 256, 0, stream>>>(ei_tj + E_TJ, E_TJ, cur_cj);
    k_count<<<(E_JJ / 4 + 255) / 256, 256, 0, stream>>>(ei_jj + E_JJ, E_JJ, cur_cj);

    auto scan = [&](int* cur, int* off, int n) {
        int nb = (n + 1023) / 1024;
        k_bsum<<<nb, 1024, 0, stream>>>(cur, n, bsum);
        k_scan_bsum<<<1, 1024, 0, stream>>>(bsum, nb);
        k_scan_final<<<nb, 1024, 0, stream>>>(cur, n, bsum, off, cur);
    };
    scan(cur_jt, off_jt, NT);
    scan(cur_cj, off_cj, NJ);

    k_fill<<<(E_JT / 4 + 255) / 256, 256, 0, stream>>>(ei_jt, ei_jt + E_JT, E_JT, cur_jt, src_jt, 0);
    // combined joint CSR: tj sources -> Q rows [0,NT); jj sources -> P rows via +NT
    k_fill<<<(E_TJ / 4 + 255) / 256, 256, 0, stream>>>(ei_tj, ei_tj + E_TJ, E_TJ, cur_cj, src_cj, 0);
    k_fill<<<(E_JJ / 4 + 255) / 256, 256, 0, stream>>>(ei_jj, ei_jj + E_JJ, E_JJ, cur_cj, src_cj, NT);

    // ---- input linears ----
    k_in_linear<<<2048, 256, 0, stream>>>(x_t, w0_t, b0_t, h_t, NT);
    k_in_linear<<<2048, 256, 0, stream>>>(x_j, w0_j, b0_j, h_j, NJ);

    // ---- 2 hetero GraphConv layers ----
    for (int l = 0; l < 2; ++l) {
        const float* tj_rel_w  = (const float*)d_in[9 + l * 9 + 0];
        const float* tj_rel_b  = (const float*)d_in[9 + l * 9 + 1];
        const float* tj_root_w = (const float*)d_in[9 + l * 9 + 2];
        const float* jt_rel_w  = (const float*)d_in[9 + l * 9 + 3];
        const float* jt_rel_b  = (const float*)d_in[9 + l * 9 + 4];
        const float* jt_root_w = (const float*)d_in[9 + l * 9 + 5];
        const float* jj_rel_w  = (const float*)d_in[9 + l * 9 + 6];
        const float* jj_rel_b  = (const float*)d_in[9 + l * 9 + 7];
        const float* jj_root_w = (const float*)d_in[9 + l * 9 + 8];

        k_prep<<<17, 256, 0, stream>>>(tj_root_w, jj_root_w, tj_rel_b, jj_rel_b, wcomb, bcomb);

        // Q = old h_t @ W_tj ; h_t <- old h_t @ root_jt + b_jt   (R_t in place)
        k_transform2<<<2048, 256, 0, stream>>>(h_t, tj_rel_w, jt_root_w, jt_rel_b, Q, NT);
        // P = h_j @ W_jt
        k_transform<<<2048, 256, 0, stream>>>(h_j, jt_rel_w, P, NJ);
        // h_t = tanh( gather_jt(P) + h_t )
        k_aggadd<<<2048, 256, 0, stream>>>(P, h_t, off_jt, src_jt, NT);
        // P = h_j @ W_jj ; h_j <- h_j @ wcomb + bcomb   (R_j in place; old P consumed above)
        k_transform2<<<2048, 256, 0, stream>>>(h_j, jj_rel_w, wcomb, bcomb, P, NJ);
        // h_j = tanh( gather_cj([Q;P]) + h_j )
        k_aggadd<<<2048, 256, 0, stream>>>(Q, h_j, off_cj, src_cj, NJ);
    }

    // ---- output heads ----
    float* out = (float*)d_out;
    k_out<<<2048, 256, 0, stream>>>(h_t, w3_t, b3_t,
                                    out, out + (size_t)NT * 8, NT);
    k_out<<<2048, 256, 0, stream>>>(h_j, w3_j, b3_j,
                                    out + (size_t)2 * NT * 8,
                                    out + (size_t)2 * NT * 8 + (size_t)NJ * 8, NJ);
}